// Round 7
// baseline (286.893 us; speedup 1.0000x reference)
//
#include <hip/hip_runtime.h>
#include <math.h>

// Round 7: dependency-breaking on both waves (structure of round 6 kept:
// 4-step-unrolled producer/consumer, one barrier per 4 steps, stores deferred
// one iteration).
//   wave0: zr window loads prefetched ONE SUB-STEP ahead -> conv issue stream
//          (~145 cyc) hides the LDS latency completely.
//   wave1: s_part LDS round-trip replaced by 3x __shfl_down + __fadd_rn in the
//          exact ((p0+p1)+p2)+p3 order; decoder state lives at lane 4o (no
//          gather hop). pv reads double-buffered one sub-step ahead.
// All FP chains keep byte-identical operation order -> numerics unchanged.
// Requires T % 4 == 0 (T=300).

typedef float v2f __attribute__((ext_vector_type(2)));

__global__ __launch_bounds__(128, 4) void snn_step_kernel(
    const float* __restrict__ x,       // [B,1,15,15]
    const float* __restrict__ conv_w,  // [2,1,4,4]
    const float* __restrict__ conv_b,  // [2]
    const float* __restrict__ lin_w,   // [10,72]
    const float* __restrict__ lin_b,   // [10]
    float* __restrict__ out,           // spk_out[B,10] ++ mem_rec[T,B,10] ++ spk_rec[T,B,10]
    int T, int B)
{
    const int b   = blockIdx.x;
    const int tid = threadIdx.x;
    const int w   = tid & 63;   // lane within wave
    const int wv  = tid >> 6;   // 0 = enc+conv wave, 1 = lin+dec wave

    __shared__ float s_convw[32];
    __shared__ float s_convb[2];
    __shared__ float s_linw[720];
    __shared__ float s_linb[10];
    __shared__ float s_z[2][304];   // wave0-private, double-buffered swizzled 15x15 (+pad)
    __shared__ float s_p[8][72];    // wave0 -> wave1 handoff, 8-deep

    // ---- cooperative weight staging (128 threads) ----
    if (tid < 32) s_convw[tid] = conv_w[tid];
    if (tid < 2)  s_convb[tid] = conv_b[tid];
    for (int j = tid; j < 720; j += 128) s_linw[j] = lin_w[j];
    if (tid < 10) s_linb[tid] = lin_b[tid];
    __syncthreads();

    // ===== wave0 state =====
    float ve[4], cur[4];
    int   zoff[4];
    v2f   wreg2[16];
    v2f   cb2 = (v2f){0.0f, 0.0f};
    int   wbase = 0;
    bool  convlane = false;
    float zrbuf[2][25];             // double-buffered conv window registers

    // ===== wave1 state =====
    // output o's decoder state lives at lane 4o (o = w>>2, lanes 0,4,...,36)
    float lwreg[18];
    float lbias = 0.0f;
    float v = 0.0f, i_syn = 0.0f, sc = 0.0f;
    float svv[4], svs[4];           // deferred store values per sub-step
    const int o  = w >> 2, lq = w & 3;
    const bool olane = ((w & 3) == 0) && (w < 40);
    const size_t BO = (size_t)B * 10;
    float* mp  = out + BO + (size_t)b * 10 + (olane ? o : 0);
    float* spp = mp + (size_t)T * BO;

    const int roff[5] = {0, 16, 35, 51, 70};

    if (wv == 0) {
        // encoder: lane w owns pixels w, w+64, w+128, w+192 (branchless; p>=225 -> pad)
#pragma unroll
        for (int k = 0; k < 4; ++k) {
            int p = w + 64 * k;
            bool act = (p < 225);
            ve[k]  = 0.0f;
            cur[k] = act ? __fmul_rn(x[(size_t)b * 225 + p], 10.0f) : 0.0f;
            int row = p / 15, col = p - row * 15;
            zoff[k] = row * 16 + col + 3 * (row >> 1);   // swizzle; rows>=15 land in pad
        }
        convlane = (w < 36);
        int py = w / 6, px = w - py * 6;
        int wb = 35 * py + 2 * px;
        wbase = wb < 229 ? wb : 229;   // clamp keeps dead lanes in-bounds
#pragma unroll
        for (int kk = 0; kk < 16; ++kk) wreg2[kk] = (v2f){s_convw[kk], s_convw[16 + kk]};
        cb2 = (v2f){s_convb[0], s_convb[1]};

        // prologue: enc(0) -> s_z[0], then prefetch zr(0) into zrbuf[0]
#pragma unroll
        for (int k = 0; k < 4; ++k) {
            float vn = __fadd_rn(ve[k], __fmul_rn(0.1f, __fsub_rn(cur[k], ve[k])));
            bool  sp = (vn > 1.0f);
            ve[k] = sp ? 0.0f : vn;
            s_z[0][zoff[k]] = sp ? 1.0f : 0.0f;
        }
        const float* zc = &s_z[0][wbase];
#pragma unroll
        for (int r = 0; r < 5; ++r)
#pragma unroll
            for (int cc = 0; cc < 5; ++cc)
                zrbuf[0][r * 5 + cc] = zc[roff[r] + cc];
    } else {
#pragma unroll
        for (int j = 0; j < 18; ++j) {
            int idx = o * 72 + lq * 18 + j;
            lwreg[j] = s_linw[idx < 720 ? idx : 719];   // clamp for lanes >= 40
        }
        lbias = olane ? s_linb[o] : 0.0f;
    }

    auto issue_stores = [&]() {
        if (olane) {
#pragma unroll
            for (int k = 0; k < 4; ++k) {
                mp[(size_t)k * BO]  = svv[k];
                spp[(size_t)k * BO] = svs[k];
            }
        }
        mp  += 4 * BO;
        spp += 4 * BO;
    };

    // wave1: linear+decoder for one step; pv already in registers
    auto lin_comp = [&](const float* pv, int k) {
        float partial = 0.0f;
#pragma unroll
        for (int j = 0; j < 18; ++j)
            partial = fmaf(lwreg[j], pv[j], partial);
        // exact ((p0+p1)+p2)+p3 at lane 4o via shfl_down (bit-exact moves)
        float t = partial;
        t = __fadd_rn(t, __shfl_down(partial, 1));
        t = __fadd_rn(t, __shfl_down(partial, 2));
        t = __fadd_rn(t, __shfl_down(partial, 3));
        float lin = __fadd_rn(t, lbias);

        float vd  = __fadd_rn(v, __fmul_rn(0.1f, __fsub_rn(i_syn, v)));
        float id  = __fsub_rn(i_syn, __fmul_rn(0.2f, i_syn));
        float spk = (vd > 1.0f) ? 1.0f : 0.0f;
        v = (vd > 1.0f) ? 0.0f : vd;
        sc += spk;
        svv[k] = v;
        svs[k] = spk;
        i_syn = __fadd_rn(id, lin);
    };

    const int TI = T >> 2;   // T % 4 == 0

    for (int i = 0; i < TI; ++i) {
        if (wv == 0) {
#pragma unroll
            for (int k = 0; k < 4; ++k) {
                // encoder for step 4i+k+1 -> s_z[(k+1)&1]
#pragma unroll
                for (int kk = 0; kk < 4; ++kk) {
                    float vn = __fadd_rn(ve[kk], __fmul_rn(0.1f, __fsub_rn(cur[kk], ve[kk])));
                    bool  sp = (vn > 1.0f);
                    ve[kk] = sp ? 0.0f : vn;
                    s_z[(k + 1) & 1][zoff[kk]] = sp ? 1.0f : 0.0f;
                }
                // prefetch zr(4i+k+1) (reads follow the enc writes in the DS queue)
                {
                    const float* zc = &s_z[(k + 1) & 1][wbase];
#pragma unroll
                    for (int r = 0; r < 5; ++r)
#pragma unroll
                        for (int cc = 0; cc < 5; ++cc)
                            zrbuf[(k + 1) & 1][r * 5 + cc] = zc[roff[r] + cc];
                }
                // conv 4x4 (channels packed) + maxpool 2x2 for step 4i+k,
                // using zrbuf[k&1] loaded one sub-step ago (latency hidden)
                if (convlane) {
                    const float* zr = zrbuf[k & 1];
                    v2f m2 = (v2f){-INFINITY, -INFINITY};
#pragma unroll
                    for (int dy = 0; dy < 2; ++dy)
#pragma unroll
                        for (int dx = 0; dx < 2; ++dx) {
                            v2f acc = (v2f){0.0f, 0.0f};
#pragma unroll
                            for (int ky = 0; ky < 4; ++ky)
#pragma unroll
                                for (int kx = 0; kx < 4; ++kx) {
                                    float z = zr[(dy + ky) * 5 + (dx + kx)];
                                    acc = __builtin_elementwise_fma(wreg2[ky * 4 + kx],
                                                                    (v2f){z, z}, acc);
                                }
                            v2f val = acc + cb2;
                            m2 = __builtin_elementwise_max(m2, val);
                        }
                    float* pbuf = s_p[((i & 1) << 2) | k];
                    pbuf[w]      = m2.x;
                    pbuf[36 + w] = m2.y;
                }
            }
        } else {
            if (i >= 2) issue_stores();            // steps 4(i-2)..4(i-2)+3
            if (i >= 1) {
                const int sbase = ((i - 1) & 1) << 2;
                float pvbuf[2][18];
                // prefetch k=0
                {
                    const float* pp = &s_p[sbase][lq * 18];
#pragma unroll
                    for (int j = 0; j < 18; ++j) pvbuf[0][j] = pp[j];
                }
#pragma unroll
                for (int k = 0; k < 4; ++k) {
                    if (k < 3) {                    // prefetch k+1 before k's fma chain
                        const float* pp = &s_p[sbase | (k + 1)][lq * 18];
#pragma unroll
                        for (int j = 0; j < 18; ++j) pvbuf[(k + 1) & 1][j] = pp[j];
                    }
                    lin_comp(pvbuf[k & 1], k);      // steps 4(i-1)..4(i-1)+3
                }
            }
        }
        __syncthreads();
    }

    // ---- epilogue (wave1): pending stores T-8..T-5, compute+store T-4..T-1 ----
    if (wv == 1) {
        issue_stores();                             // steps T-8..T-5
        const int sbase = ((TI - 1) & 1) << 2;
#pragma unroll
        for (int k = 0; k < 4; ++k) {
            float pv[18];
            const float* pp = &s_p[sbase | k][lq * 18];
#pragma unroll
            for (int j = 0; j < 18; ++j) pv[j] = pp[j];
            lin_comp(pv, k);                        // steps T-4..T-1
        }
        issue_stores();
        if (olane) out[(size_t)b * 10 + o] = sc;
    }
}

extern "C" void kernel_launch(void* const* d_in, const int* in_sizes, int n_in,
                              void* d_out, int out_size, void* d_ws, size_t ws_size,
                              hipStream_t stream) {
    const float* x      = (const float*)d_in[0];
    const float* conv_w = (const float*)d_in[1];
    const float* conv_b = (const float*)d_in[2];
    const float* lin_w  = (const float*)d_in[3];
    const float* lin_b  = (const float*)d_in[4];
    float* out = (float*)d_out;

    const int B = in_sizes[0] / 225;             // x is [B,1,15,15]
    const int T = (out_size / (B * 10) - 1) / 2; // out = B*10 * (1 + 2T); T=300 (div by 4)

    snn_step_kernel<<<B, 128, 0, stream>>>(x, conv_w, conv_b, lin_w, lin_b, out, T, B);
}